// Round 2
// baseline (289.911 us; speedup 1.0000x reference)
//
#include <hip/hip_runtime.h>

#define NN 35
#define GRID 512

// packed fp32 helpers (v_pk_fma_f32 — half-rate on gfx950, kept for code density)
typedef float v2f __attribute__((ext_vector_type(2)));

__device__ __forceinline__ v2f pk_fma(v2f a, v2f b, v2f c) {
#if __has_builtin(__builtin_elementwise_fma)
    return __builtin_elementwise_fma(a, b, c);
#else
    v2f d; d.x = fmaf(a.x, b.x, c.x); d.y = fmaf(a.y, b.y, c.y); return d;
#endif
}
__device__ __forceinline__ v2f pk_relu(v2f a) {
    v2f d; d.x = fmaxf(a.x, 0.f); d.y = fmaxf(a.y, 0.f); return d;
}
__device__ __forceinline__ v2f pk_splat(float s) { v2f d; d.x = s; d.y = s; return d; }
__device__ __forceinline__ v2f pk_make(float a, float b) { v2f d; d.x = a; d.y = b; return d; }

// agent-scope (device) atomics for cross-XCD visibility of workspace arrays
__device__ __forceinline__ float agld(const float* p) {
    return __hip_atomic_load(p, __ATOMIC_RELAXED, __HIP_MEMORY_SCOPE_AGENT);
}
__device__ __forceinline__ void agst(float* p, float v) {
    __hip_atomic_store(p, v, __ATOMIC_RELAXED, __HIP_MEMORY_SCOPE_AGENT);
}

// ws layout (floats): agg2[35*256]=8960 | agg3[35*128]=4480 | h1[35*512]=17920 | bar[2 u32]
// offsets:            0                | 8960               | 13440            | 31360

// ---------------- init: zero aggs + barrier state (ws is poisoned each iter) --------
__global__ __launch_bounds__(256)
void init_kernel(float* __restrict__ ws) {
    const int i = blockIdx.x * 256 + threadIdx.x;
    if (i < 35 * 384) ws[i] = 0.f;                       // agg2 + agg3
    if (i < 2) ((unsigned*)(ws + 31360))[i] = 0u;        // barrier cnt / gen
}

// ---------------- grid barrier (all blocks co-resident; device-scope) --------------
__device__ __forceinline__ void gbar(unsigned* cnt, unsigned* gen, unsigned nb) {
    __syncthreads();
    if (threadIdx.x == 0) {
        __threadfence();   // release prior writes to device scope
        const unsigned g = __hip_atomic_load(gen, __ATOMIC_RELAXED, __HIP_MEMORY_SCOPE_AGENT);
        const unsigned a = __hip_atomic_fetch_add(cnt, 1u, __ATOMIC_ACQ_REL, __HIP_MEMORY_SCOPE_AGENT);
        if (a == nb - 1u) {
            __hip_atomic_store(cnt, 0u, __ATOMIC_RELAXED, __HIP_MEMORY_SCOPE_AGENT);
            __hip_atomic_fetch_add(gen, 1u, __ATOMIC_RELEASE, __HIP_MEMORY_SCOPE_AGENT);
        } else {
            while (__hip_atomic_load(gen, __ATOMIC_RELAXED, __HIP_MEMORY_SCOPE_AGENT) == g)
                __builtin_amdgcn_s_sleep(2);
        }
        __threadfence();   // acquire
    }
    __syncthreads();
}

// ---------------- fused kernel: L1 -> bar -> E2 -> bar -> E3 -> bar -> CBT ----------
__global__ __launch_bounds__(256, 2)
void fused_kernel(const float* __restrict__ x,      // [35,1]
                  const float* __restrict__ ea,     // [1190,4]
                  const float* __restrict__ W1, const float* __restrict__ b1,
                  const float* __restrict__ root1, const float* __restrict__ bias1,
                  const float* __restrict__ W2, const float* __restrict__ b2,
                  const float* __restrict__ root2, const float* __restrict__ bias2,
                  const float* __restrict__ W3, const float* __restrict__ b3,
                  const float* __restrict__ root3, const float* __restrict__ bias3,
                  float* __restrict__ out,          // [35,35]
                  float* __restrict__ ws)
{
    float* agg2 = ws;
    float* agg3 = ws + 8960;
    float* h1   = ws + 13440;
    unsigned* bar = (unsigned*)(ws + 31360);
    const unsigned nb = gridDim.x;
    const int thr = threadIdx.x;

    __shared__ __align__(16) float hs[35][8];
    __shared__ float4 as[34];

    // ---------- phase 1: layer 1 (1 -> 512) ----------
    for (int gt = blockIdx.x * 256 + thr; gt < 35 * 512; gt += gridDim.x * 256) {
        const int d = gt >> 9, o = gt & 511;
        const float w0 = W1[o], w1 = W1[512 + o], w2 = W1[1024 + o], w3 = W1[1536 + o];
        const float bb = b1[o];
        float sum = 0.f;
#pragma unroll
        for (int s = 0; s < NN; ++s) {
            if (s == d) continue;
            const float4 a = ((const float4*)ea)[s * 34 + (d < s ? d : d - 1)];
            float w = fmaf(a.x, w0, fmaf(a.y, w1, fmaf(a.z, w2, fmaf(a.w, w3, bb))));
            sum = fmaf(x[s], fmaxf(w, 0.f), sum);
        }
        agst(&h1[gt], fmaxf(sum * (1.f / 34.f) + x[d] * root1[o] + bias1[o], 0.f));
    }

    gbar(bar, bar + 1, nb);

    // ---------- phase 2: layer 2 (512 -> 256), IC=8, 2240 virtual tiles ----------
    for (int t = blockIdx.x; t < 35 * 64; t += gridDim.x) {
        const int d  = t % 35;
        const int c  = t / 35;
        const int i0 = c * 8;
        const int o  = thr;

        __syncthreads();   // protect LDS from previous tile's readers
        if (thr < 70) {
            const int r = thr >> 1, k = thr & 1;
            const int s = (r < 34) ? (r + (r >= d ? 1 : 0)) : d;   // row 34 = d itself
#pragma unroll
            for (int q = 0; q < 4; ++q)
                hs[r][k * 4 + q] = agld(&h1[s * 512 + i0 + k * 4 + q]);
        }
        if (thr >= 70 && thr < 104) {
            const int j = thr - 70;
            const int s = j + (j >= d ? 1 : 0);
            as[j] = ((const float4*)ea)[s * 34 + (d < s ? d : d - 1)];
        }
        __syncthreads();

        v2f Wv0[4], Wv1[4], Wv2[4], Wv3[4], BB[4], RR[4];
#pragma unroll
        for (int p = 0; p < 4; ++p) {
            const size_t b0 = (size_t)(i0 + 2 * p) * 256 + o;
            const size_t bq = b0 + 256;
            Wv0[p] = pk_make(W2[b0],          W2[bq]);
            Wv1[p] = pk_make(W2[131072 + b0], W2[131072 + bq]);
            Wv2[p] = pk_make(W2[262144 + b0], W2[262144 + bq]);
            Wv3[p] = pk_make(W2[393216 + b0], W2[393216 + bq]);
            BB[p]  = pk_make(b2[b0],          b2[bq]);
            RR[p]  = pk_make(root2[b0],       root2[bq]);
        }

        v2f acc0 = pk_splat(0.f), acc1 = pk_splat(0.f);
#pragma unroll 2
        for (int j = 0; j < 34; ++j) {
            const float4 a = as[j];
            const v2f ax = pk_splat(a.x), ay = pk_splat(a.y);
            const v2f az = pk_splat(a.z), aw = pk_splat(a.w);
#pragma unroll
            for (int k = 0; k < 2; ++k) {
                const float4 hv = ((const float4*)hs[j])[k];
                {
                    const int p = k * 2;
                    v2f w = pk_fma(ax, Wv0[p], pk_fma(ay, Wv1[p],
                            pk_fma(az, Wv2[p], pk_fma(aw, Wv3[p], BB[p]))));
                    acc0 = pk_fma(pk_make(hv.x, hv.y), pk_relu(w), acc0);
                }
                {
                    const int p = k * 2 + 1;
                    v2f w = pk_fma(ax, Wv0[p], pk_fma(ay, Wv1[p],
                            pk_fma(az, Wv2[p], pk_fma(aw, Wv3[p], BB[p]))));
                    acc1 = pk_fma(pk_make(hv.z, hv.w), pk_relu(w), acc1);
                }
            }
        }
        v2f racc = pk_splat(0.f);
#pragma unroll
        for (int k = 0; k < 2; ++k) {
            const float4 hv = ((const float4*)hs[34])[k];
            racc = pk_fma(pk_make(hv.x, hv.y), RR[k * 2],     racc);
            racc = pk_fma(pk_make(hv.z, hv.w), RR[k * 2 + 1], racc);
        }
        const float acc = acc0.x + acc0.y + acc1.x + acc1.y;
        atomicAdd(&agg2[d * 256 + o], acc * (1.f / 34.f) + (racc.x + racc.y));
    }

    gbar(bar, bar + 1, nb);

    // ---------- phase 3: layer 3 (256 -> 128), act2 fused, IC=8 (two i-halves) ------
    for (int t = blockIdx.x; t < 35 * 32; t += gridDim.x) {
        const int d  = t % 35;
        const int c  = t / 35;
        const int i0 = c * 8;
        const int o  = thr & 127;
        const int g  = thr >> 7;          // i-half: 0 -> i0..i0+3, 1 -> i0+4..i0+7

        __syncthreads();
        if (thr < 70) {
            const int r = thr >> 1, k = thr & 1;
            const int s = (r < 34) ? (r + (r >= d ? 1 : 0)) : d;
#pragma unroll
            for (int q = 0; q < 4; ++q) {
                const int f = i0 + k * 4 + q;
                hs[r][k * 4 + q] = fmaxf(agld(&agg2[s * 256 + f]) + bias2[f], 0.f);
            }
        }
        if (thr >= 70 && thr < 104) {
            const int j = thr - 70;
            const int s = j + (j >= d ? 1 : 0);
            as[j] = ((const float4*)ea)[s * 34 + (d < s ? d : d - 1)];
        }
        __syncthreads();

        v2f Wv0[2], Wv1[2], Wv2[2], Wv3[2], BB[2], RR[2];
#pragma unroll
        for (int p = 0; p < 2; ++p) {
            const size_t b0 = (size_t)(i0 + g * 4 + 2 * p) * 128 + o;
            const size_t bq = b0 + 128;
            Wv0[p] = pk_make(W3[b0],         W3[bq]);
            Wv1[p] = pk_make(W3[32768 + b0], W3[32768 + bq]);
            Wv2[p] = pk_make(W3[65536 + b0], W3[65536 + bq]);
            Wv3[p] = pk_make(W3[98304 + b0], W3[98304 + bq]);
            BB[p]  = pk_make(b3[b0],         b3[bq]);
            RR[p]  = pk_make(root3[b0],      root3[bq]);
        }

        v2f acc0 = pk_splat(0.f), acc1 = pk_splat(0.f);
#pragma unroll 2
        for (int j = 0; j < 34; ++j) {
            const float4 a = as[j];
            const v2f ax = pk_splat(a.x), ay = pk_splat(a.y);
            const v2f az = pk_splat(a.z), aw = pk_splat(a.w);
            const float4 hv = ((const float4*)hs[j])[g];
            {
                v2f w = pk_fma(ax, Wv0[0], pk_fma(ay, Wv1[0],
                        pk_fma(az, Wv2[0], pk_fma(aw, Wv3[0], BB[0]))));
                acc0 = pk_fma(pk_make(hv.x, hv.y), pk_relu(w), acc0);
            }
            {
                v2f w = pk_fma(ax, Wv0[1], pk_fma(ay, Wv1[1],
                        pk_fma(az, Wv2[1], pk_fma(aw, Wv3[1], BB[1]))));
                acc1 = pk_fma(pk_make(hv.z, hv.w), pk_relu(w), acc1);
            }
        }
        v2f racc = pk_splat(0.f);
        {
            const float4 hv = ((const float4*)hs[34])[g];
            racc = pk_fma(pk_make(hv.x, hv.y), RR[0], racc);
            racc = pk_fma(pk_make(hv.z, hv.w), RR[1], racc);
        }
        const float acc = acc0.x + acc0.y + acc1.x + acc1.y;
        atomicAdd(&agg3[d * 128 + o], acc * (1.f / 34.f) + (racc.x + racc.y));
    }

    gbar(bar, bar + 1, nb);

    // ---------- phase 4: pairwise L1, act3 fused; one wave per pair ----------
    const int lane = thr & 63;
    for (int wv = blockIdx.x * 4 + (thr >> 6); wv < NN * NN; wv += gridDim.x * 4) {
        const int a_ = wv / NN, i_ = wv % NN;
        float s = 0.f;
#pragma unroll
        for (int q = 0; q < 2; ++q) {
            const int f = lane + q * 64;
            const float bb = bias3[f];
            const float hi = fmaxf(agld(&agg3[i_ * 128 + f]) + bb, 0.f);
            const float ha = fmaxf(agld(&agg3[a_ * 128 + f]) + bb, 0.f);
            s += fabsf(hi - ha);
        }
#pragma unroll
        for (int off = 32; off > 0; off >>= 1)
            s += __shfl_xor(s, off, 64);
        if (lane == 0) out[wv] = s;
    }
}

extern "C" void kernel_launch(void* const* d_in, const int* in_sizes, int n_in,
                              void* d_out, int out_size, void* d_ws, size_t ws_size,
                              hipStream_t stream) {
    const float* x      = (const float*)d_in[0];
    const float* ea     = (const float*)d_in[1];
    const float* mlp1_w = (const float*)d_in[3];
    const float* mlp1_b = (const float*)d_in[4];
    const float* root1  = (const float*)d_in[5];
    const float* bias1  = (const float*)d_in[6];
    const float* mlp2_w = (const float*)d_in[7];
    const float* mlp2_b = (const float*)d_in[8];
    const float* root2  = (const float*)d_in[9];
    const float* bias2  = (const float*)d_in[10];
    const float* mlp3_w = (const float*)d_in[11];
    const float* mlp3_b = (const float*)d_in[12];
    const float* root3  = (const float*)d_in[13];
    const float* bias3  = (const float*)d_in[14];
    float* out = (float*)d_out;
    float* ws  = (float*)d_ws;

    // zero aggs + barrier words (ws is poisoned each iteration)
    init_kernel<<<53, 256, 0, stream>>>(ws);
    // single persistent kernel: 512 blocks x 256 thr, 2 blocks/CU -> all co-resident
    fused_kernel<<<GRID, 256, 0, stream>>>(x, ea,
                                           mlp1_w, mlp1_b, root1, bias1,
                                           mlp2_w, mlp2_b, root2, bias2,
                                           mlp3_w, mlp3_b, root3, bias3,
                                           out, ws);
}

// Round 3
// 170.769 us; speedup vs baseline: 1.6977x; 1.6977x over previous
//
#include <hip/hip_runtime.h>

#define NN 35

// packed fp32 helpers (v_pk_fma_f32)
typedef float v2f __attribute__((ext_vector_type(2)));

__device__ __forceinline__ v2f pk_fma(v2f a, v2f b, v2f c) {
#if __has_builtin(__builtin_elementwise_fma)
    return __builtin_elementwise_fma(a, b, c);
#else
    v2f d; d.x = fmaf(a.x, b.x, c.x); d.y = fmaf(a.y, b.y, c.y); return d;
#endif
}
__device__ __forceinline__ v2f pk_relu(v2f a) {
    v2f d; d.x = fmaxf(a.x, 0.f); d.y = fmaxf(a.y, 0.f); return d;
}
__device__ __forceinline__ v2f pk_splat(float s) { v2f d; d.x = s; d.y = s; return d; }
__device__ __forceinline__ v2f pk_make(float a, float b) { v2f d; d.x = a; d.y = b; return d; }

__device__ __forceinline__ float agld(const float* p) {
    return __hip_atomic_load(p, __ATOMIC_RELAXED, __HIP_MEMORY_SCOPE_AGENT);
}

// ws layout (floats): part[32][35][256] = 286720 | agg3[35*128] = 4480 | cnt (1 u32)

// ============ Kernel A: layer1 (redundant per block) + layer2, partial out ==========
__global__ __launch_bounds__(256, 2)
void fused12_kernel(const float* __restrict__ x,      // [35,1]
                    const float* __restrict__ ea,     // [1190,4]
                    const float* __restrict__ W1, const float* __restrict__ b1,
                    const float* __restrict__ root1, const float* __restrict__ bias1,
                    const float* __restrict__ W2, const float* __restrict__ b2,
                    const float* __restrict__ root2,
                    float* __restrict__ part,         // [32][35][256]
                    float* __restrict__ agg3,         // [35*128] zeroed here
                    unsigned* __restrict__ cnt)       // zeroed here
{
    const int d  = blockIdx.x;
    const int c  = blockIdx.y;
    const int i0 = c * 16;
    const int o  = threadIdx.x;
    const int bid = c * 35 + d;

    __shared__ __align__(16) float4 eas[1190];
    __shared__ __align__(16) float hs[35][16];
    __shared__ float xs[35];

    if (o < 4) agg3[bid * 4 + o] = 0.f;           // 1120*4 = 4480 exactly
    if (bid == 0 && o == 4) *cnt = 0u;

    for (int e = o; e < 1190; e += 256) eas[e] = ((const float4*)ea)[e];
    if (o < 35) xs[o] = x[o];
    __syncthreads();

    // redundant layer 1: h1[s][i0+ii] for all s, ii<16 (560 values)
    for (int e = o; e < 560; e += 256) {
        const int s = e >> 4, ii = e & 15, i = i0 + ii;
        const float w0 = W1[i], w1 = W1[512 + i], w2 = W1[1024 + i], w3 = W1[1536 + i];
        const float bb = b1[i];
        float sum = 0.f;
#pragma unroll
        for (int t = 0; t < NN; ++t) {
            if (t == s) continue;
            const float4 a = eas[t * 34 + (s < t ? s : s - 1)];
            float w = fmaf(a.x, w0, fmaf(a.y, w1, fmaf(a.z, w2, fmaf(a.w, w3, bb))));
            sum = fmaf(xs[t], fmaxf(w, 0.f), sum);
        }
        hs[s][ii] = fmaxf(sum * (1.f / 34.f) + xs[s] * root1[i] + bias1[i], 0.f);
    }

    v2f Wv0[8], Wv1[8], Wv2[8], Wv3[8], BB[8], RR[8];
#pragma unroll
    for (int p = 0; p < 8; ++p) {
        const size_t b0 = (size_t)(i0 + 2 * p) * 256 + o;
        const size_t bq = b0 + 256;
        Wv0[p] = pk_make(W2[b0],          W2[bq]);
        Wv1[p] = pk_make(W2[131072 + b0], W2[131072 + bq]);
        Wv2[p] = pk_make(W2[262144 + b0], W2[262144 + bq]);
        Wv3[p] = pk_make(W2[393216 + b0], W2[393216 + bq]);
        BB[p]  = pk_make(b2[b0],          b2[bq]);
        RR[p]  = pk_make(root2[b0],       root2[bq]);
    }
    __syncthreads();

    v2f acc0 = pk_splat(0.f), acc1 = pk_splat(0.f);
#pragma unroll 2
    for (int j = 0; j < 34; ++j) {
        const int sj = j + (j >= d ? 1 : 0);
        const float4 a = eas[sj * 34 + (d < sj ? d : d - 1)];
        const v2f ax = pk_splat(a.x), ay = pk_splat(a.y);
        const v2f az = pk_splat(a.z), aw = pk_splat(a.w);
#pragma unroll
        for (int k = 0; k < 4; ++k) {
            const float4 hv = ((const float4*)hs[sj])[k];
            {
                const int p = k * 2;
                v2f w = pk_fma(ax, Wv0[p], pk_fma(ay, Wv1[p],
                        pk_fma(az, Wv2[p], pk_fma(aw, Wv3[p], BB[p]))));
                acc0 = pk_fma(pk_make(hv.x, hv.y), pk_relu(w), acc0);
            }
            {
                const int p = k * 2 + 1;
                v2f w = pk_fma(ax, Wv0[p], pk_fma(ay, Wv1[p],
                        pk_fma(az, Wv2[p], pk_fma(aw, Wv3[p], BB[p]))));
                acc1 = pk_fma(pk_make(hv.z, hv.w), pk_relu(w), acc1);
            }
        }
    }
    v2f racc = pk_splat(0.f);
#pragma unroll
    for (int k = 0; k < 4; ++k) {
        const float4 hv = ((const float4*)hs[d])[k];
        racc = pk_fma(pk_make(hv.x, hv.y), RR[k * 2],     racc);
        racc = pk_fma(pk_make(hv.z, hv.w), RR[k * 2 + 1], racc);
    }
    const float acc = acc0.x + acc0.y + acc1.x + acc1.y;
    part[(size_t)bid * 256 + o] = acc * (1.f / 34.f) + (racc.x + racc.y);
}

// ============ Kernel B: layer3 (partial-sum stage, act2 fused) + cbt tail ===========
__global__ __launch_bounds__(256, 2)
void fused34_kernel(const float* __restrict__ ea,
                    const float* __restrict__ part,   // [32][35][256]
                    const float* __restrict__ bias2,  // [256]
                    const float* __restrict__ W3, const float* __restrict__ b3,
                    const float* __restrict__ root3, const float* __restrict__ bias3,
                    float* __restrict__ agg3,         // [35*128]
                    unsigned* __restrict__ cnt,
                    float* __restrict__ out)          // [35,35]
{
    const int d  = blockIdx.x;
    const int c  = blockIdx.y;
    const int i0 = c * 8;
    const int thr = threadIdx.x;
    const int o  = thr & 127;
    const int g  = thr >> 7;          // i-half: 0 -> i0..i0+3, 1 -> i0+4..i0+7

    __shared__ __align__(16) float hs[35][8];
    __shared__ __align__(16) float4 as[34];
    __shared__ __align__(16) float rel3[35][128];
    __shared__ unsigned lastflag;

    // stage h2 = relu(sum_c part + bias2) for this i-chunk: 280 elements
    for (int e = thr; e < 280; e += 256) {
        const int s = e >> 3, f = i0 + (e & 7);
        float v = 0.f;
#pragma unroll
        for (int cc = 0; cc < 32; ++cc) v += part[(size_t)(cc * 35 + s) * 256 + f];
        hs[s][e & 7] = fmaxf(v + bias2[f], 0.f);
    }
    if (thr < 34) {
        const int s = thr + (thr >= d ? 1 : 0);
        as[thr] = ((const float4*)ea)[s * 34 + (d < s ? d : d - 1)];
    }
    __syncthreads();

    v2f Wv0[2], Wv1[2], Wv2[2], Wv3[2], BB[2], RR[2];
#pragma unroll
    for (int p = 0; p < 2; ++p) {
        const size_t b0 = (size_t)(i0 + g * 4 + 2 * p) * 128 + o;
        const size_t bq = b0 + 128;
        Wv0[p] = pk_make(W3[b0],         W3[bq]);
        Wv1[p] = pk_make(W3[32768 + b0], W3[32768 + bq]);
        Wv2[p] = pk_make(W3[65536 + b0], W3[65536 + bq]);
        Wv3[p] = pk_make(W3[98304 + b0], W3[98304 + bq]);
        BB[p]  = pk_make(b3[b0],         b3[bq]);
        RR[p]  = pk_make(root3[b0],      root3[bq]);
    }

    v2f acc0 = pk_splat(0.f), acc1 = pk_splat(0.f);
#pragma unroll 2
    for (int j = 0; j < 34; ++j) {
        const int sj = j + (j >= d ? 1 : 0);
        const float4 a = as[j];
        const v2f ax = pk_splat(a.x), ay = pk_splat(a.y);
        const v2f az = pk_splat(a.z), aw = pk_splat(a.w);
        const float4 hv = ((const float4*)hs[sj])[g];
        {
            v2f w = pk_fma(ax, Wv0[0], pk_fma(ay, Wv1[0],
                    pk_fma(az, Wv2[0], pk_fma(aw, Wv3[0], BB[0]))));
            acc0 = pk_fma(pk_make(hv.x, hv.y), pk_relu(w), acc0);
        }
        {
            v2f w = pk_fma(ax, Wv0[1], pk_fma(ay, Wv1[1],
                    pk_fma(az, Wv2[1], pk_fma(aw, Wv3[1], BB[1]))));
            acc1 = pk_fma(pk_make(hv.z, hv.w), pk_relu(w), acc1);
        }
    }
    v2f racc = pk_splat(0.f);
    {
        const float4 hv = ((const float4*)hs[d])[g];
        racc = pk_fma(pk_make(hv.x, hv.y), RR[0], racc);
        racc = pk_fma(pk_make(hv.z, hv.w), RR[1], racc);
    }
    const float acc = acc0.x + acc0.y + acc1.x + acc1.y;
    atomicAdd(&agg3[d * 128 + o], acc * (1.f / 34.f) + (racc.x + racc.y));

    // ---- last-block cbt tail ----
    __syncthreads();
    if (thr == 0) {
        __threadfence();
        lastflag = (atomicAdd(cnt, 1u) == 35u * 32u - 1u) ? 1u : 0u;
    }
    __syncthreads();
    if (!lastflag) return;
    __threadfence();

    for (int e = thr; e < 35 * 128; e += 256)
        ((float*)rel3)[e] = fmaxf(agld(&agg3[e]) + bias3[e & 127], 0.f);
    __syncthreads();

    for (int idx = thr; idx < NN * NN; idx += 256) {
        const int a_ = idx / NN, i_ = idx % NN;
        if (a_ > i_) continue;
        float s = 0.f;
#pragma unroll
        for (int k = 0; k < 32; ++k) {
            const float4 va = ((const float4*)rel3[a_])[k];
            const float4 vi = ((const float4*)rel3[i_])[k];
            s += fabsf(vi.x - va.x) + fabsf(vi.y - va.y)
               + fabsf(vi.z - va.z) + fabsf(vi.w - va.w);
        }
        out[a_ * NN + i_] = s;
        out[i_ * NN + a_] = s;
    }
}

extern "C" void kernel_launch(void* const* d_in, const int* in_sizes, int n_in,
                              void* d_out, int out_size, void* d_ws, size_t ws_size,
                              hipStream_t stream) {
    const float* x      = (const float*)d_in[0];
    const float* ea     = (const float*)d_in[1];
    const float* mlp1_w = (const float*)d_in[3];
    const float* mlp1_b = (const float*)d_in[4];
    const float* root1  = (const float*)d_in[5];
    const float* bias1  = (const float*)d_in[6];
    const float* mlp2_w = (const float*)d_in[7];
    const float* mlp2_b = (const float*)d_in[8];
    const float* root2  = (const float*)d_in[9];
    const float* bias2  = (const float*)d_in[10];
    const float* mlp3_w = (const float*)d_in[11];
    const float* mlp3_b = (const float*)d_in[12];
    const float* root3  = (const float*)d_in[13];
    const float* bias3  = (const float*)d_in[14];
    float* out = (float*)d_out;

    float* ws   = (float*)d_ws;
    float* part = ws;                       // 32*35*256 = 286720
    float* agg3 = ws + 286720;              // 35*128 = 4480
    unsigned* cnt = (unsigned*)(ws + 286720 + 4480);

    fused12_kernel<<<dim3(NN, 32), 256, 0, stream>>>(
        x, ea, mlp1_w, mlp1_b, root1, bias1, mlp2_w, mlp2_b, root2,
        part, agg3, cnt);
    fused34_kernel<<<dim3(NN, 32), 256, 0, stream>>>(
        ea, part, bias2, mlp3_w, mlp3_b, root3, bias3,
        agg3, cnt, out);
}